// Round 1
// baseline (469.435 us; speedup 1.0000x reference)
//
#include <hip/hip_runtime.h>
#include <hip/hip_bf16.h>
#include <cmath>

typedef __bf16 bf16x8 __attribute__((ext_vector_type(8)));
typedef __bf16 bf16x4 __attribute__((ext_vector_type(4)));
typedef float f32x4 __attribute__((ext_vector_type(4)));

#define GLOBAL_AS __attribute__((address_space(1)))
#define LDS_AS __attribute__((address_space(3)))

__device__ __forceinline__ void async_copy16(const void* g, void* l) {
    __builtin_amdgcn_global_load_lds((const GLOBAL_AS void*)g, (LDS_AS void*)l, 16, 0, 0);
}

#define SBAR() asm volatile("s_barrier" ::: "memory")
#define WAITLGKM0() asm volatile("s_waitcnt lgkmcnt(0)" ::: "memory")

// ---------------------------------------------------------------------------
// SEQ_idxes may be int64 or int32. As int32 words, int64 layout =
// [f0_lo, f0_hi(=0), ...]; int32 layout = [f0, s0(>=2049), ...]. seq[1]==0 <=> int64.
__device__ inline int get_first(const int* __restrict__ seq, int b) {
    int stride = (seq[1] == 0) ? 4 : 2;
    return seq[b * stride];
}

// ---------------------------------------------------------------------------
__global__ __launch_bounds__(256) void cast_f32_bf16(const float* __restrict__ in,
                                                     __bf16* __restrict__ out, int n4) {
    int i = blockIdx.x * 256 + threadIdx.x;
    if (i >= n4) return;
    float4 v = ((const float4*)in)[i];
    bf16x4 o;
    o[0] = (__bf16)v.x; o[1] = (__bf16)v.y; o[2] = (__bf16)v.z; o[3] = (__bf16)v.w;
    ((bf16x4*)out)[i] = o;
}

__global__ __launch_bounds__(256) void cast3_f32_bf16(
    const float* __restrict__ a, const float* __restrict__ b, const float* __restrict__ c,
    __bf16* __restrict__ oa, __bf16* __restrict__ ob, __bf16* __restrict__ oc, int n4) {
    int i = blockIdx.x * 256 + threadIdx.x;
    if (i >= n4) return;
    const float* in = (blockIdx.y == 0) ? a : (blockIdx.y == 1) ? b : c;
    __bf16* out = (blockIdx.y == 0) ? oa : (blockIdx.y == 1) ? ob : oc;
    float4 v = ((const float4*)in)[i];
    bf16x4 o;
    o[0] = (__bf16)v.x; o[1] = (__bf16)v.y; o[2] = (__bf16)v.z; o[3] = (__bf16)v.w;
    ((bf16x4*)out)[i] = o;
}

__global__ __launch_bounds__(256) void zero_f32(float* __restrict__ p, int n4) {
    int i = blockIdx.x * 256 + threadIdx.x;
    if (i < n4) ((f32x4*)p)[i] = f32x4{0.f, 0.f, 0.f, 0.f};
}

// ---------------------------------------------------------------------------
// gemm_bt: 128x128 tile, 2-barrier structure (kept for the small K/V projections).
// EPI: 0 = bf16 + bias; 1 = bf16 TRANSPOSED (C[n][m]) + bias.
template <int EPI>
__global__ __launch_bounds__(256) void gemm_bt(
    const __bf16* __restrict__ A, int lda, long strideA,
    const __bf16* __restrict__ B, int ldb, long strideB,
    const float* __restrict__ bias,
    void* __restrict__ Cv, int ldc, long strideC,
    int Kfix, const int* __restrict__ seq, int exit_mode, int k_mode,
    float cs, float* __restrict__ rowsum) {
    int z = blockIdx.z;
    int m0 = blockIdx.x * 128, n0 = blockIdx.y * 128;
    int first = seq ? get_first(seq, z) : 0;
    if (exit_mode == 1 && m0 >= first) return;
    if (exit_mode == 2 && n0 >= first) return;
    int K = k_mode ? ((first + 63) & ~63) : Kfix;

    __shared__ char As[16384];
    __shared__ char Bs[16384];

    int tid = threadIdx.x;
    int lane = tid & 63, wid = tid >> 6;
    int waveM = (wid & 1) << 6, waveN = (wid >> 1) << 6;
    int quad = lane >> 4, l16 = lane & 15;

    int r0 = tid >> 3;
    int c8 = (tid & 7) ^ (r0 & 7);
    const __bf16* Ag = A + (long)z * strideA + (long)(m0 + r0) * lda + c8 * 8;
    const __bf16* Bg = B + (long)z * strideB + (long)(n0 + r0) * ldb + c8 * 8;

    f32x4 acc[4][4] = {};
    int xorv = (l16 & 7) << 4;

    for (int k0 = 0; k0 < K; k0 += 64) {
        __syncthreads();
#pragma unroll
        for (int r = 0; r < 4; ++r) {
            async_copy16(Ag + (long)(r * 32) * lda + k0, As + (tid + r * 256) * 16);
            async_copy16(Bg + (long)(r * 32) * ldb + k0, Bs + (tid + r * 256) * 16);
        }
        __syncthreads();
#pragma unroll
        for (int s = 0; s < 2; ++s) {
            bf16x8 af[4], bfr[4];
#pragma unroll
            for (int i = 0; i < 4; ++i) {
                int chunk = (((s << 2) + quad) << 4) ^ xorv;
                af[i]  = *(const bf16x8*)(As + (waveM + i * 16 + l16) * 128 + chunk);
                bfr[i] = *(const bf16x8*)(Bs + (waveN + i * 16 + l16) * 128 + chunk);
            }
#pragma unroll
            for (int i = 0; i < 4; ++i)
#pragma unroll
                for (int j = 0; j < 4; ++j)
                    acc[i][j] = __builtin_amdgcn_mfma_f32_16x16x32_bf16(af[i], bfr[j], acc[i][j], 0, 0, 0);
        }
    }

    if (EPI == 0) {
        __bf16* C = (__bf16*)Cv + (long)z * strideC;
#pragma unroll
        for (int i = 0; i < 4; ++i) {
            int rowb = m0 + waveM + i * 16 + quad * 4;
#pragma unroll
            for (int j = 0; j < 4; ++j) {
                int col = n0 + waveN + j * 16 + l16;
                float bv_ = bias[col];
#pragma unroll
                for (int r = 0; r < 4; ++r)
                    C[(long)(rowb + r) * ldc + col] = (__bf16)(acc[i][j][r] + bv_);
            }
        }
    } else {
        __bf16* C = (__bf16*)Cv + (long)z * strideC;
#pragma unroll
        for (int i = 0; i < 4; ++i) {
            int rowb = m0 + waveM + i * 16 + quad * 4;
#pragma unroll
            for (int j = 0; j < 4; ++j) {
                int col = n0 + waveN + j * 16 + l16;
                float bv_ = bias[col];
                bf16x4 o;
#pragma unroll
                for (int r = 0; r < 4; ++r) o[r] = (__bf16)(acc[i][j][r] + bv_);
                *(bf16x4*)&C[(long)col * ldc + rowb] = o;
            }
        }
    }
}

// ---------------------------------------------------------------------------
// gemm256: 256x256 tile, BK=64, 512 threads = 8 waves (2M x 4N), per-wave 128x64.
// 4 phases per K-tile; each phase: {ds_read subtile | stage half-tile} -> barrier
// -> lgkmcnt(0) -> setprio(1) -> 16 MFMA -> setprio(0) -> barrier.  Counted vmcnt:
//   stage order per tile kt (filling buf kt+1): P1:{Ae',Be'}  P2:{Bo',Ao'}
//   waits: vmcnt(8)@P2 (retires Ao(kt) before P3's ds_reads),
//          vmcnt(2)@P4 (retires Ae',Be',Bo' before next tile's P1/P2 reads);
//   Ao' (newest 2 loads) stays in flight across the tile boundary. Never vmcnt(0)
//   mid-loop; last tile (no staging) degenerates to vmcnt(0)@P2 (block-uniform).
// Halves (row groups of 64): A-even={g0,g2} feeds P1 reads of BOTH wr halves
// (wave wr reads tile rows wr*128+0..63 at P1); A-odd={g1,g3} feeds P3.
// B-even={g0,g2} = cols 0-63,128-191 (waves wc=0,2); B-odd = waves wc=1,3; both
// B col-subhalves (qc) of a wave sit in ONE group, so both B halves are required
// at tile start -> covered by vmcnt(2)@P4 of the previous tile.
// LDS: linear [256 rows][8 chunks of 16B] per buffer, XOR chunk swizzle via
// pre-swizzled GLOBAL source (slot c holds global chunk c^(row&7)); frag read
// uses chunk (p ^ (l16&7)) -> measured 0 bank conflicts with this scheme.
// EPI: 0 = bf16 + bias; 2 = p=exp2(acc*cs) masked to [1,first), bf16 store +
//      atomic rowsum; 3 = fp32 store scaled by 1/rowsum[row].
template <int EPI>
__global__ __launch_bounds__(512, 2) void gemm256(
    const __bf16* __restrict__ A, int lda, long strideA,
    const __bf16* __restrict__ B, int ldb, long strideB,
    const float* __restrict__ bias,
    void* __restrict__ Cv, int ldc, long strideC,
    int Kfix, const int* __restrict__ seq, int exit_mode, int k_mode,
    float cs, float* __restrict__ rowsum) {
    int z = blockIdx.z;
    int m0 = blockIdx.x * 256, n0 = blockIdx.y * 256;
    int first = seq ? get_first(seq, z) : 0;
    if (exit_mode == 2 && n0 >= first) return;
    int K = k_mode ? ((first + 63) & ~63) : Kfix;
    int nt = K >> 6;

    __shared__ char As[2][32768];
    __shared__ char Bs[2][32768];

    int tid = threadIdx.x;
    int lane = tid & 63, wid = tid >> 6;
    int wr = (wid >> 2) << 7;   // 0 or 128
    int wc = (wid & 3) << 6;    // 0,64,128,192
    int quad = lane >> 4, l16 = lane & 15;
    int xr = l16 & 7;

    // staging: thread -> row (tid>>3) within a 64-row group, chunk slot tid&7;
    // global source chunk pre-swizzled so LDS[r][c] holds global chunk c^(r&7).
    int rg = tid >> 3;
    int src_c8 = (tid & 7) ^ (rg & 7);
    const __bf16* Ag = A + (long)z * strideA + (long)(m0 + rg) * lda + src_c8 * 8;
    const __bf16* Bg = B + (long)z * strideB + (long)(n0 + rg) * ldb + src_c8 * 8;

#define STAGE_A(bb, g, kk) async_copy16(Ag + (long)((g) * 64) * lda + (kk), &As[bb][(g) * 8192 + tid * 16])
#define STAGE_B(bb, g, kk) async_copy16(Bg + (long)((g) * 64) * ldb + (kk), &Bs[bb][(g) * 8192 + tid * 16])
#define AFRAG(base, row, s) (*(const bf16x8*)((base) + (row) * 128 + ((((s << 2) + quad) ^ xr) << 4)))

    f32x4 acc[8][4] = {};

    // prologue: tile0 halves in ledger order Ae,Be,Bo,Ao; vmcnt(2) leaves Ao in flight.
    STAGE_A(0, 0, 0); STAGE_A(0, 2, 0);
    STAGE_B(0, 0, 0); STAGE_B(0, 2, 0);
    STAGE_B(0, 1, 0); STAGE_B(0, 3, 0);
    STAGE_A(0, 1, 0); STAGE_A(0, 3, 0);
    asm volatile("s_waitcnt vmcnt(2)" ::: "memory");
    SBAR();

    bf16x8 a[4][2];        // current row-subhalf A frags (reloaded at P3)
    bf16x8 bq[2][2][2];    // [qc][j][s], live across the tile

    for (int kt = 0; kt < nt; ++kt) {
        int buf = kt & 1, nbuf = buf ^ 1;
        int k0n = (kt + 1) << 6;
        bool stg = (kt + 1) < nt;
        const char* Ab = &As[buf][0];
        const char* Bb = &Bs[buf][0];

        // ---- P1: read A(qh=0)+B(qc=0); stage Ae',Be'
#pragma unroll
        for (int i = 0; i < 4; ++i)
#pragma unroll
            for (int s = 0; s < 2; ++s)
                a[i][s] = AFRAG(Ab, wr + i * 16 + l16, s);
#pragma unroll
        for (int j = 0; j < 2; ++j)
#pragma unroll
            for (int s = 0; s < 2; ++s)
                bq[0][j][s] = AFRAG(Bb, wc + j * 16 + l16, s);
        if (stg) { STAGE_A(nbuf, 0, k0n); STAGE_A(nbuf, 2, k0n); STAGE_B(nbuf, 0, k0n); STAGE_B(nbuf, 2, k0n); }
        SBAR();
        WAITLGKM0();
        __builtin_amdgcn_s_setprio(1);
#pragma unroll
        for (int i = 0; i < 4; ++i)
#pragma unroll
            for (int j = 0; j < 2; ++j)
#pragma unroll
                for (int s = 0; s < 2; ++s)
                    acc[i][j] = __builtin_amdgcn_mfma_f32_16x16x32_bf16(a[i][s], bq[0][j][s], acc[i][j], 0, 0, 0);
        __builtin_amdgcn_s_setprio(0);
        SBAR();

        // ---- P2: read B(qc=1); stage Bo',Ao' (Ao' LAST); vmcnt(8) retires Ao(kt)
#pragma unroll
        for (int j = 0; j < 2; ++j)
#pragma unroll
            for (int s = 0; s < 2; ++s)
                bq[1][j][s] = AFRAG(Bb, wc + 32 + j * 16 + l16, s);
        if (stg) {
            STAGE_B(nbuf, 1, k0n); STAGE_B(nbuf, 3, k0n);
            STAGE_A(nbuf, 1, k0n); STAGE_A(nbuf, 3, k0n);
            asm volatile("s_waitcnt vmcnt(8)" ::: "memory");
        } else {
            asm volatile("s_waitcnt vmcnt(0)" ::: "memory");
        }
        SBAR();
        WAITLGKM0();
        __builtin_amdgcn_s_setprio(1);
#pragma unroll
        for (int i = 0; i < 4; ++i)
#pragma unroll
            for (int j = 0; j < 2; ++j)
#pragma unroll
                for (int s = 0; s < 2; ++s)
                    acc[i][2 + j] = __builtin_amdgcn_mfma_f32_16x16x32_bf16(a[i][s], bq[1][j][s], acc[i][2 + j], 0, 0, 0);
        __builtin_amdgcn_s_setprio(0);
        SBAR();

        // ---- P3: read A(qh=1) (guaranteed by P2's vmcnt)
#pragma unroll
        for (int i = 0; i < 4; ++i)
#pragma unroll
            for (int s = 0; s < 2; ++s)
                a[i][s] = AFRAG(Ab, wr + 64 + i * 16 + l16, s);
        SBAR();
        WAITLGKM0();
        __builtin_amdgcn_s_setprio(1);
#pragma unroll
        for (int i = 0; i < 4; ++i)
#pragma unroll
            for (int j = 0; j < 2; ++j)
#pragma unroll
                for (int s = 0; s < 2; ++s)
                    acc[4 + i][j] = __builtin_amdgcn_mfma_f32_16x16x32_bf16(a[i][s], bq[0][j][s], acc[4 + i][j], 0, 0, 0);
        __builtin_amdgcn_s_setprio(0);
        SBAR();

        // ---- P4: no reads; vmcnt(2) retires Ae',Be',Bo' for next tile's P1/P2
        asm volatile("s_waitcnt vmcnt(2)" ::: "memory");
        SBAR();
        __builtin_amdgcn_s_setprio(1);
#pragma unroll
        for (int i = 0; i < 4; ++i)
#pragma unroll
            for (int j = 0; j < 2; ++j)
#pragma unroll
                for (int s = 0; s < 2; ++s)
                    acc[4 + i][2 + j] = __builtin_amdgcn_mfma_f32_16x16x32_bf16(a[i][s], bq[1][j][s], acc[4 + i][2 + j], 0, 0, 0);
        __builtin_amdgcn_s_setprio(0);
        SBAR();
    }
#undef STAGE_A
#undef STAGE_B
#undef AFRAG

    // C/D frag: col = l16 (n), row = quad*4 + reg (m). [m89-verified]
    if (EPI == 0) {
        __bf16* C = (__bf16*)Cv + (long)z * strideC;
#pragma unroll
        for (int i = 0; i < 8; ++i) {
            int rowb = m0 + wr + i * 16 + quad * 4;
#pragma unroll
            for (int j = 0; j < 4; ++j) {
                int col = n0 + wc + j * 16 + l16;
                float bv_ = bias[col];
#pragma unroll
                for (int r = 0; r < 4; ++r)
                    C[(long)(rowb + r) * ldc + col] = (__bf16)(acc[i][j][r] + bv_);
            }
        }
    } else if (EPI == 2) {
        __bf16* C = (__bf16*)Cv + (long)z * strideC;
        float* rsum = rowsum + (long)z * 4096;
#pragma unroll
        for (int i = 0; i < 8; ++i) {
            int rowb = m0 + wr + i * 16 + quad * 4;
            float sum[4] = {0.f, 0.f, 0.f, 0.f};
#pragma unroll
            for (int j = 0; j < 4; ++j) {
                int col = n0 + wc + j * 16 + l16;
                bool valid = (col >= 1) && (col < first);
#pragma unroll
                for (int r = 0; r < 4; ++r) {
                    float e = valid ? exp2f(acc[i][j][r] * cs) : 0.0f;
                    __bf16 pb = (__bf16)e;
                    C[(long)(rowb + r) * ldc + col] = pb;
                    sum[r] += (float)pb;  // sum the bf16-rounded value (consistent w/ PV)
                }
            }
#pragma unroll
            for (int r = 0; r < 4; ++r) {
                float v = sum[r];
                v += __shfl_xor(v, 8); v += __shfl_xor(v, 4);
                v += __shfl_xor(v, 2); v += __shfl_xor(v, 1);
                if (l16 == 0) atomicAdd(&rsum[rowb + r], v);
            }
        }
    } else {
        float* C = (float*)Cv + (long)z * strideC;
        const float* rsum = rowsum + (long)z * 4096;
#pragma unroll
        for (int i = 0; i < 8; ++i) {
            int rowb = m0 + wr + i * 16 + quad * 4;
            float inv[4];
#pragma unroll
            for (int r = 0; r < 4; ++r) inv[r] = 1.0f / rsum[rowb + r];
#pragma unroll
            for (int j = 0; j < 4; ++j) {
                int col = n0 + wc + j * 16 + l16;
#pragma unroll
                for (int r = 0; r < 4; ++r)
                    C[(long)(rowb + r) * ldc + col] = acc[i][j][r] * inv[r];
            }
        }
    }
}

// ---------------------------------------------------------------------------
extern "C" void kernel_launch(void* const* d_in, const int* in_sizes, int n_in,
                              void* d_out, int out_size, void* d_ws, size_t ws_size,
                              hipStream_t stream) {
    const int B = 8, S = 4096, E = 768, SK = 2048;
    const float* ebd  = (const float*)d_in[0];
    const int*   seq  = (const int*)d_in[1];
    const float* Wq_w = (const float*)d_in[2];
    const float* Wq_b = (const float*)d_in[3];
    const float* Wk_w = (const float*)d_in[4];
    const float* Wk_b = (const float*)d_in[5];
    const float* Wv_w = (const float*)d_in[6];
    const float* Wv_b = (const float*)d_in[7];
    float* out = (float*)d_out;

    char* p = (char*)d_ws;
    __bf16* ebd_bf = (__bf16*)p; p += (size_t)B * S * E * 2;   // 50.3 MB
    __bf16* wq = (__bf16*)p;     p += (size_t)E * E * 2;
    __bf16* wk = (__bf16*)p;     p += (size_t)E * E * 2;
    __bf16* wv = (__bf16*)p;     p += (size_t)E * E * 2;
    __bf16* Qb = (__bf16*)p;     p += (size_t)B * S * E * 2;   // 50.3 MB
    __bf16* Kb = (__bf16*)p;     p += (size_t)B * SK * E * 2;  // 25.2 MB
    __bf16* VT = (__bf16*)p;     p += (size_t)B * E * SK * 2;  // 25.2 MB  V^T: [b][e][k]
    __bf16* Pb = (__bf16*)p;     p += (size_t)B * S * SK * 2;  // 134.2 MB exp-scores
    float* rowsum = (float*)p;   p += (size_t)B * S * 4;       // 128 KB

    zero_f32<<<B * S / 4 / 256, 256, 0, stream>>>(rowsum, B * S / 4);
    cast_f32_bf16<<<(B * S * E / 4 + 255) / 256, 256, 0, stream>>>(ebd, ebd_bf, B * S * E / 4);
    cast3_f32_bf16<<<dim3((E * E / 4 + 255) / 256, 3), 256, 0, stream>>>(
        Wq_w, Wk_w, Wv_w, wq, wk, wv, E * E / 4);

    float cs = (1.0f / sqrtf((float)E)) * 1.44269504088896f;  // scale * log2(e)

    // Q = ebd @ Wq^T + bq  (M = B*S as one GEMM) [256² pipelined]
    gemm256<0><<<dim3(B * S / 256, E / 256, 1), 512, 0, stream>>>(
        ebd_bf, E, 0, wq, E, 0, Wq_b, Qb, E, 0, E, nullptr, 0, 0, 0.f, nullptr);
    // K[b] = ebd[b,0:2048] @ Wk^T + bk  (skip m-tiles >= first) [128²]
    gemm_bt<0><<<dim3(SK / 128, E / 128, B), 256, 0, stream>>>(
        ebd_bf, E, (long)S * E, wk, E, 0, Wk_b, Kb, E, (long)SK * E, E, seq, 1, 0, 0.f, nullptr);
    // VT[b] = (ebd[b,0:2048] @ Wv^T + bv)^T [128²]
    gemm_bt<1><<<dim3(SK / 128, E / 128, B), 256, 0, stream>>>(
        ebd_bf, E, (long)S * E, wv, E, 0, Wv_b, VT, SK, (long)E * SK, E, seq, 1, 0, 0.f, nullptr);
    // P[b] = exp(Q K^T * scale) masked to [1,first), + rowsum atomics [256²]
    gemm256<2><<<dim3(S / 256, SK / 256, B), 512, 0, stream>>>(
        Qb, E, (long)S * E, Kb, E, (long)SK * E, nullptr, Pb, SK, (long)S * SK, E, seq, 2, 0, cs, rowsum);
    // out[b] = (P[b] @ V[b]) / rowsum  (K bounded to roundup64(first)) [256²]
    gemm256<3><<<dim3(S / 256, E / 256, B), 512, 0, stream>>>(
        Pb, SK, (long)S * SK, VT, SK, (long)E * SK, nullptr, out, E, (long)S * E, 0, seq, 0, 1, 0.f, rowsum);
}

// Round 2
// 410.317 us; speedup vs baseline: 1.1441x; 1.1441x over previous
//
#include <hip/hip_runtime.h>
#include <hip/hip_bf16.h>
#include <cmath>

typedef __bf16 bf16x8 __attribute__((ext_vector_type(8)));
typedef __bf16 bf16x4 __attribute__((ext_vector_type(4)));
typedef float f32x4 __attribute__((ext_vector_type(4)));

#define GLOBAL_AS __attribute__((address_space(1)))
#define LDS_AS __attribute__((address_space(3)))

__device__ __forceinline__ void async_copy16(const void* g, void* l) {
    __builtin_amdgcn_global_load_lds((const GLOBAL_AS void*)g, (LDS_AS void*)l, 16, 0, 0);
}

// ---------------------------------------------------------------------------
// SEQ_idxes may be int64 or int32. As int32 words, int64 layout =
// [f0_lo, f0_hi(=0), ...]; int32 layout = [f0, s0(>=2049), ...]. seq[1]==0 <=> int64.
__device__ inline int get_first(const int* __restrict__ seq, int b) {
    int stride = (seq[1] == 0) ? 4 : 2;
    return seq[b * stride];
}

// ---------------------------------------------------------------------------
__global__ __launch_bounds__(256) void cast_f32_bf16(const float* __restrict__ in,
                                                     __bf16* __restrict__ out, int n4) {
    int i = blockIdx.x * 256 + threadIdx.x;
    if (i >= n4) return;
    float4 v = ((const float4*)in)[i];
    bf16x4 o;
    o[0] = (__bf16)v.x; o[1] = (__bf16)v.y; o[2] = (__bf16)v.z; o[3] = (__bf16)v.w;
    ((bf16x4*)out)[i] = o;
}

// 3 weight matrices in one dispatch (blockIdx.y selects)
__global__ __launch_bounds__(256) void cast3_f32_bf16(
    const float* __restrict__ a, const float* __restrict__ b, const float* __restrict__ c,
    __bf16* __restrict__ oa, __bf16* __restrict__ ob, __bf16* __restrict__ oc, int n4) {
    int i = blockIdx.x * 256 + threadIdx.x;
    if (i >= n4) return;
    const float* in = (blockIdx.y == 0) ? a : (blockIdx.y == 1) ? b : c;
    __bf16* out = (blockIdx.y == 0) ? oa : (blockIdx.y == 1) ? ob : oc;
    float4 v = ((const float4*)in)[i];
    bf16x4 o;
    o[0] = (__bf16)v.x; o[1] = (__bf16)v.y; o[2] = (__bf16)v.z; o[3] = (__bf16)v.w;
    ((bf16x4*)out)[i] = o;
}

__global__ __launch_bounds__(256) void zero_f32(float* __restrict__ p, int n4) {
    int i = blockIdx.x * 256 + threadIdx.x;
    if (i < n4) ((f32x4*)p)[i] = f32x4{0.f, 0.f, 0.f, 0.f};
}

// ---------------------------------------------------------------------------
// gemm_bt: C[m][n] = sum_k A[m][k] * Bt[n][k]  (+ bias[n])
// 128x128 tile, BK=64, 256 threads = 4 waves (2x2), wave = 4x4 of 16x16x32 MFMA.
// RESIDENCY-TUNED: __launch_bounds__(256,4) caps the unified VGPR+AGPR budget
// at 128/wave (acc = 64 AGPR + ~50 arch) -> 4 blocks/CU instead of 2 (the
// 156-reg version rounded to the 256-reg quantum -> 2 waves/SIMD, m69 model).
// More resident blocks = the latency-hiding the 2-barrier structure needs:
// each K-step drains vmcnt(0) at the barrier (~900cy first-touch loads), so
// duty cycle ~= resident_waves * 154cy / 900cy.
// Inner loop keeps only 5 frag regs live (bfr[4] + streaming af) instead of 16.
// Staging: global_load_lds width=16; LDS XOR-swizzled via the GLOBAL source
// index (dest must stay linear). Frag reads use the matching XOR -> 0 conflicts
// (measured R0/R1).
// EPI: 0 = bf16 + bias; 1 = bf16 TRANSPOSED (C[n][m]) + bias;
//      2 = p=exp2(acc*cs) masked to [1,first), bf16 store + atomic rowsum;
//      3 = fp32 store scaled by 1/rowsum[row].
// exit_mode: 0 none, 1 skip if m0>=first, 2 skip if n0>=first.
// k_mode: 0 K=Kfix, 1 K=roundup64(first).
template <int EPI>
__global__ __launch_bounds__(256, 4) void gemm_bt(
    const __bf16* __restrict__ A, int lda, long strideA,
    const __bf16* __restrict__ B, int ldb, long strideB,
    const float* __restrict__ bias,
    void* __restrict__ Cv, int ldc, long strideC,
    int Kfix, const int* __restrict__ seq, int exit_mode, int k_mode,
    float cs, float* __restrict__ rowsum) {
    int z = blockIdx.z;
    int m0 = blockIdx.x * 128, n0 = blockIdx.y * 128;
    int first = seq ? get_first(seq, z) : 0;
    if (exit_mode == 1 && m0 >= first) return;
    if (exit_mode == 2 && n0 >= first) return;
    int K = k_mode ? ((first + 63) & ~63) : Kfix;

    __shared__ char As[16384];
    __shared__ char Bs[16384];

    int tid = threadIdx.x;
    int lane = tid & 63, wid = tid >> 6;
    int waveM = (wid & 1) << 6, waveN = (wid >> 1) << 6;
    int quad = lane >> 4, l16 = lane & 15;

    // staging source: row r0 (+32 per round), swizzled 16B-chunk c8 (round-invariant)
    int r0 = tid >> 3;
    int c8 = (tid & 7) ^ (r0 & 7);
    const __bf16* Ag = A + (long)z * strideA + (long)(m0 + r0) * lda + c8 * 8;
    const __bf16* Bg = B + (long)z * strideB + (long)(n0 + r0) * ldb + c8 * 8;

    f32x4 acc[4][4] = {};
    int xorv = (l16 & 7) << 4;  // frag-read swizzle (byte units)

    for (int k0 = 0; k0 < K; k0 += 64) {
        __syncthreads();  // prior iter's ds_reads done before overwrite
#pragma unroll
        for (int r = 0; r < 4; ++r) {
            async_copy16(Ag + (long)(r * 32) * lda + k0, As + (tid + r * 256) * 16);
            async_copy16(Bg + (long)(r * 32) * ldb + k0, Bs + (tid + r * 256) * 16);
        }
        __syncthreads();  // drains vmcnt (compiler emits waitcnt before barrier)
#pragma unroll
        for (int s = 0; s < 2; ++s) {
            int chunk = (((s << 2) + quad) << 4) ^ xorv;
            bf16x8 bfr[4];
#pragma unroll
            for (int j = 0; j < 4; ++j)
                bfr[j] = *(const bf16x8*)(Bs + (waveN + j * 16 + l16) * 128 + chunk);
#pragma unroll
            for (int i = 0; i < 4; ++i) {
                bf16x8 af = *(const bf16x8*)(As + (waveM + i * 16 + l16) * 128 + chunk);
#pragma unroll
                for (int j = 0; j < 4; ++j)
                    acc[i][j] = __builtin_amdgcn_mfma_f32_16x16x32_bf16(af, bfr[j], acc[i][j], 0, 0, 0);
            }
        }
    }

    // C/D frag: col = l16 (n), row = quad*4 + reg (m). [m89-verified]
    if (EPI == 0) {
        __bf16* C = (__bf16*)Cv + (long)z * strideC;
#pragma unroll
        for (int i = 0; i < 4; ++i) {
            int rowb = m0 + waveM + i * 16 + quad * 4;
#pragma unroll
            for (int j = 0; j < 4; ++j) {
                int col = n0 + waveN + j * 16 + l16;
                float bv_ = bias[col];
#pragma unroll
                for (int r = 0; r < 4; ++r)
                    C[(long)(rowb + r) * ldc + col] = (__bf16)(acc[i][j][r] + bv_);
            }
        }
    } else if (EPI == 1) {
        __bf16* C = (__bf16*)Cv + (long)z * strideC;
#pragma unroll
        for (int i = 0; i < 4; ++i) {
            int rowb = m0 + waveM + i * 16 + quad * 4;
#pragma unroll
            for (int j = 0; j < 4; ++j) {
                int col = n0 + waveN + j * 16 + l16;
                float bv_ = bias[col];
                bf16x4 o;
#pragma unroll
                for (int r = 0; r < 4; ++r) o[r] = (__bf16)(acc[i][j][r] + bv_);
                *(bf16x4*)&C[(long)col * ldc + rowb] = o;  // rowb%4==0 -> 8B aligned
            }
        }
    } else if (EPI == 2) {
        __bf16* C = (__bf16*)Cv + (long)z * strideC;
        float* rs = rowsum + (long)z * 4096;
#pragma unroll
        for (int i = 0; i < 4; ++i) {
            int rowb = m0 + waveM + i * 16 + quad * 4;
            float sum[4] = {0.f, 0.f, 0.f, 0.f};
#pragma unroll
            for (int j = 0; j < 4; ++j) {
                int col = n0 + waveN + j * 16 + l16;
                bool valid = (col >= 1) && (col < first);
#pragma unroll
                for (int r = 0; r < 4; ++r) {
                    float e = valid ? exp2f(acc[i][j][r] * cs) : 0.0f;
                    __bf16 pb = (__bf16)e;
                    C[(long)(rowb + r) * ldc + col] = pb;
                    sum[r] += (float)pb;  // sum the bf16-rounded value (consistent w/ PV)
                }
            }
#pragma unroll
            for (int r = 0; r < 4; ++r) {
                float v = sum[r];
                v += __shfl_xor(v, 8); v += __shfl_xor(v, 4);
                v += __shfl_xor(v, 2); v += __shfl_xor(v, 1);
                if (l16 == 0) atomicAdd(&rs[rowb + r], v);
            }
        }
    } else {
        float* C = (float*)Cv + (long)z * strideC;
        const float* rs = rowsum + (long)z * 4096;
#pragma unroll
        for (int i = 0; i < 4; ++i) {
            int rowb = m0 + waveM + i * 16 + quad * 4;
            float inv[4];
#pragma unroll
            for (int r = 0; r < 4; ++r) inv[r] = 1.0f / rs[rowb + r];
#pragma unroll
            for (int j = 0; j < 4; ++j) {
                int col = n0 + waveN + j * 16 + l16;
#pragma unroll
                for (int r = 0; r < 4; ++r)
                    C[(long)(rowb + r) * ldc + col] = acc[i][j][r] * inv[r];
            }
        }
    }
}

// ---------------------------------------------------------------------------
extern "C" void kernel_launch(void* const* d_in, const int* in_sizes, int n_in,
                              void* d_out, int out_size, void* d_ws, size_t ws_size,
                              hipStream_t stream) {
    const int B = 8, S = 4096, E = 768, SK = 2048;
    const float* ebd  = (const float*)d_in[0];
    const int*   seq  = (const int*)d_in[1];
    const float* Wq_w = (const float*)d_in[2];
    const float* Wq_b = (const float*)d_in[3];
    const float* Wk_w = (const float*)d_in[4];
    const float* Wk_b = (const float*)d_in[5];
    const float* Wv_w = (const float*)d_in[6];
    const float* Wv_b = (const float*)d_in[7];
    float* out = (float*)d_out;

    char* p = (char*)d_ws;
    __bf16* ebd_bf = (__bf16*)p; p += (size_t)B * S * E * 2;   // 50.3 MB
    __bf16* wq = (__bf16*)p;     p += (size_t)E * E * 2;
    __bf16* wk = (__bf16*)p;     p += (size_t)E * E * 2;
    __bf16* wv = (__bf16*)p;     p += (size_t)E * E * 2;
    __bf16* Qb = (__bf16*)p;     p += (size_t)B * S * E * 2;   // 50.3 MB
    __bf16* Kb = (__bf16*)p;     p += (size_t)B * SK * E * 2;  // 25.2 MB
    __bf16* VT = (__bf16*)p;     p += (size_t)B * E * SK * 2;  // 25.2 MB  V^T: [b][e][k]
    __bf16* Pb = (__bf16*)p;     p += (size_t)B * S * SK * 2;  // 134.2 MB exp-scores
    float* rowsum = (float*)p;   p += (size_t)B * S * 4;       // 128 KB

    zero_f32<<<B * S / 4 / 256, 256, 0, stream>>>(rowsum, B * S / 4);
    cast_f32_bf16<<<(B * S * E / 4 + 255) / 256, 256, 0, stream>>>(ebd, ebd_bf, B * S * E / 4);
    cast3_f32_bf16<<<dim3((E * E / 4 + 255) / 256, 3), 256, 0, stream>>>(
        Wq_w, Wk_w, Wv_w, wq, wk, wv, E * E / 4);

    float cs = (1.0f / sqrtf((float)E)) * 1.44269504088896f;  // scale * log2(e)

    // Q = ebd @ Wq^T + bq  (M = B*S as one GEMM)
    gemm_bt<0><<<dim3(B * S / 128, E / 128, 1), 256, 0, stream>>>(
        ebd_bf, E, 0, wq, E, 0, Wq_b, Qb, E, 0, E, nullptr, 0, 0, 0.f, nullptr);
    // K[b] = ebd[b,0:2048] @ Wk^T + bk  (skip m-tiles >= first)
    gemm_bt<0><<<dim3(SK / 128, E / 128, B), 256, 0, stream>>>(
        ebd_bf, E, (long)S * E, wk, E, 0, Wk_b, Kb, E, (long)SK * E, E, seq, 1, 0, 0.f, nullptr);
    // VT[b] = (ebd[b,0:2048] @ Wv^T + bv)^T
    gemm_bt<1><<<dim3(SK / 128, E / 128, B), 256, 0, stream>>>(
        ebd_bf, E, (long)S * E, wv, E, 0, Wv_b, VT, SK, (long)E * SK, E, seq, 1, 0, 0.f, nullptr);
    // P[b] = exp(Q K^T * scale) masked to [1,first), + rowsum atomics
    gemm_bt<2><<<dim3(S / 128, SK / 128, B), 256, 0, stream>>>(
        Qb, E, (long)S * E, Kb, E, (long)SK * E, nullptr, Pb, SK, (long)S * SK, E, seq, 2, 0, cs, rowsum);
    // out[b] = (P[b] @ V[b]) / rowsum  (K bounded to roundup64(first))
    gemm_bt<3><<<dim3(S / 128, E / 128, B), 256, 0, stream>>>(
        Pb, SK, (long)S * SK, VT, SK, (long)E * SK, nullptr, out, E, (long)S * E, 0, seq, 0, 1, 0.f, rowsum);
}